// Round 1
// baseline (172.403 us; speedup 1.0000x reference)
//
#include <hip/hip_runtime.h>

#define NB 16
#define NS 8191
#define SP1 8192
#define NE 768
#define HALF 384
#define VPR (NE / 4)   // 192 float4 per row

// Kernel 1: per-batch max of pos[b, :, 0] -> maxsec[b]
__global__ __launch_bounds__(256) void maxsec_kernel(const int* __restrict__ pos,
                                                     int* __restrict__ maxsec) {
    int b = blockIdx.x;
    int t = threadIdx.x;
    const int* p = pos + (size_t)b * NS * 3;
    int m = 0;
    for (int s = t; s < NS; s += 256) {
        int v = p[s * 3];
        m = v > m ? v : m;
    }
    __shared__ int sm[256];
    sm[t] = m;
    __syncthreads();
    for (int off = 128; off > 0; off >>= 1) {
        if (t < off) {
            int o = sm[t + off];
            if (o > sm[t]) sm[t] = o;
        }
        __syncthreads();
    }
    if (t == 0) maxsec[b] = sm[0];
}

// Kernel 2: out[b,s,:] = x[b,s,:] + pos_embedding + sec
// grid = (SP1, NB), block = 192 threads, one float4 per thread.
__global__ __launch_bounds__(192) void posembed_kernel(const float4* __restrict__ x,
                                                       const int* __restrict__ pos,
                                                       const float* __restrict__ pe,
                                                       const int* __restrict__ maxsec,
                                                       float4* __restrict__ out) {
    const int s = blockIdx.x;
    const int b = blockIdx.y;
    const int e4 = threadIdx.x;

    size_t idx = ((size_t)b * SP1 + s) * VPR + e4;
    float4 xv = x[idx];

    if (s == 0) {
        out[idx] = xv;
        return;
    }

    // block-uniform row metadata
    const int* pr = pos + ((size_t)b * NS + (s - 1)) * 3;
    int p0 = pr[0];
    int i1 = pr[1];
    int i2 = pr[2];
    int ms = maxsec[b];
    unsigned stride = (unsigned)(ms + 1);

    float4 o;
    float* op = (float*)&o;
    const float* xp = (const float*)&xv;

#pragma unroll
    for (int j = 0; j < 4; ++j) {
        int e = e4 * 4 + j;
        // positional embedding half-split (384 % 4 == 0 -> branch uniform per thread)
        float emb = (e < HALF) ? pe[i1 * HALF + e] : pe[i2 * HALF + (e - HALF)];
        // sec term: flipped along E
        int d = (NE - 1 - e) - p0;
        float sec = 0.0f;
        if (ms > 0 && d >= 0 && ((unsigned)d % stride) == 0u) sec = 1.0f;
        op[j] = xp[j] + emb + sec;
    }
    out[idx] = o;
}

extern "C" void kernel_launch(void* const* d_in, const int* in_sizes, int n_in,
                              void* d_out, int out_size, void* d_ws, size_t ws_size,
                              hipStream_t stream) {
    const float* x   = (const float*)d_in[0];
    const int*   pos = (const int*)d_in[1];
    const float* pe  = (const float*)d_in[2];
    float* out = (float*)d_out;
    int* maxsec = (int*)d_ws;

    maxsec_kernel<<<NB, 256, 0, stream>>>(pos, maxsec);

    dim3 grid(SP1, NB);
    posembed_kernel<<<grid, 192, 0, stream>>>((const float4*)x, pos, pe, maxsec,
                                              (float4*)out);
}

// Round 3
// 145.082 us; speedup vs baseline: 1.1883x; 1.1883x over previous
//
#include <hip/hip_runtime.h>

#define NB 16
#define NS 8191
#define SP1 8192
#define NE 768
#define HALF 384
#define VPR (NE / 4)    // 192 float4 per row
#define RPB 4           // rows per block

typedef float f32x4 __attribute__((ext_vector_type(4)));

// Kernel 1: per-batch max of pos[b, :, 0] -> ws.maxsec[b], plus magic multiplier
// for exact unsigned division by stride = maxsec+1 (valid for d <= 767, s <= 101).
__global__ __launch_bounds__(256) void maxsec_kernel(const int* __restrict__ pos,
                                                     int* __restrict__ maxsec,
                                                     unsigned* __restrict__ magics) {
    int b = blockIdx.x;
    int t = threadIdx.x;
    const int* p = pos + (size_t)b * NS * 3;
    int m = 0;
    for (int s = t; s < NS; s += 256) {
        int v = p[s * 3];
        m = v > m ? v : m;
    }
    __shared__ int sm[256];
    sm[t] = m;
    __syncthreads();
    for (int off = 128; off > 0; off >>= 1) {
        if (t < off) {
            int o = sm[t + off];
            if (o > sm[t]) sm[t] = o;
        }
        __syncthreads();
    }
    if (t == 0) {
        int ms = sm[0];
        maxsec[b] = ms;
        unsigned stride = (unsigned)(ms + 1);
        magics[b] = (0x100000u + stride - 1u) / stride;  // ceil(2^20 / stride)
    }
}

// Kernel 2: out[b,s,:] = x[b,s,:] + pos_embedding + sec
// grid = (SP1/RPB, NB), block = 192 threads, one float4 per thread per row.
__global__ __launch_bounds__(192) void posembed_kernel(const f32x4* __restrict__ x,
                                                       const int* __restrict__ pos,
                                                       const f32x4* __restrict__ pe4,
                                                       const int* __restrict__ maxsec,
                                                       const unsigned* __restrict__ magics,
                                                       f32x4* __restrict__ out) {
    const int b = blockIdx.y;
    const int s0 = blockIdx.x * RPB;
    const int t = threadIdx.x;

    const int ms = maxsec[b];
    const unsigned stride = (unsigned)(ms + 1);
    const unsigned magic = magics[b];

    const size_t base = ((size_t)b * SP1 + s0) * VPR + t;

    // Issue all row loads up front for MLP.
    f32x4 xv[RPB];
#pragma unroll
    for (int r = 0; r < RPB; ++r)
        xv[r] = __builtin_nontemporal_load(&x[base + (size_t)r * VPR]);

#pragma unroll
    for (int r = 0; r < RPB; ++r) {
        const int s = s0 + r;
        f32x4 o;
        if (s == 0) {
            o = xv[r];
        } else {
            const int* pr = pos + ((size_t)b * NS + (s - 1)) * 3;
            const int p0 = pr[0];
            const int i1 = pr[1];
            const int i2 = pr[2];

            // positional embedding: one float4 gather (alignment: i*384 floats)
            f32x4 emb = (t < HALF / 4) ? pe4[i1 * (HALF / 4) + t]
                                       : pe4[i2 * (HALF / 4) + (t - HALF / 4)];

            // sec term, flipped along E: element j has d = (767 - 4t - j) - p0
            f32x4 secs = {0.f, 0.f, 0.f, 0.f};
            const int d0 = (NE - 1) - 4 * t - p0;
            if (ms > 0 && d0 >= 0) {
                unsigned ud = (unsigned)d0;
                unsigned m = ud - stride * ((ud * magic) >> 20);  // d0 % stride (exact)
#pragma unroll
                for (int j = 0; j < 4; ++j) {
                    if (d0 - j >= 0 && m == 0u) secs[j] = 1.0f;
                    m = (m == 0u) ? stride - 1u : m - 1u;
                }
            }

            o = xv[r] + emb + secs;
        }
        __builtin_nontemporal_store(o, &out[base + (size_t)r * VPR]);
    }
}

extern "C" void kernel_launch(void* const* d_in, const int* in_sizes, int n_in,
                              void* d_out, int out_size, void* d_ws, size_t ws_size,
                              hipStream_t stream) {
    const float* x   = (const float*)d_in[0];
    const int*   pos = (const int*)d_in[1];
    const float* pe  = (const float*)d_in[2];
    float* out = (float*)d_out;
    int* maxsec = (int*)d_ws;
    unsigned* magics = (unsigned*)((char*)d_ws + NB * sizeof(int));

    maxsec_kernel<<<NB, 256, 0, stream>>>(pos, maxsec, magics);

    dim3 grid(SP1 / RPB, NB);
    posembed_kernel<<<grid, 192, 0, stream>>>((const f32x4*)x, pos,
                                              (const f32x4*)pe, maxsec, magics,
                                              (f32x4*)out);
}